// Round 8
// baseline (190.308 us; speedup 1.0000x reference)
//
#include <hip/hip_runtime.h>
#include <math.h>

#define B_ 64
#define T_ 256
#define K_ 128

typedef const __attribute__((address_space(1))) void* gas1_t;
typedef __attribute__((address_space(3))) void* las3_t;
typedef float f32x4 __attribute__((ext_vector_type(4)));
typedef short bf16x8 __attribute__((ext_vector_type(8)));

static __device__ __forceinline__ unsigned int bf16rne(float x) {
    unsigned int u = __builtin_bit_cast(unsigned int, x);
    return (u + 0x7FFFu + ((u >> 16) & 1u)) >> 16;
}
static __device__ __forceinline__ unsigned int pkbf16(float a, float b) {
    return bf16rne(a) | (bf16rne(b) << 16);
}

// ---------------------------------------------------------------------------
// Bidirectional matvec chains, ONE WAVE per chain (barrier-free).
//   forward  (dir=0): v_H = prod_{t=H..1} D_t Texp  e_SOS          (H steps)
//   backward (dir=1): z = ey_{L-1}; z <- ey_t (.) Texp^T z, t=L-2..H;
//                     w = Texp^T z                                  (L-H steps)
//   out = c_f + c_b + log(v_H . w)   (combine kernel)
// The wave holds ALL of Texp: A[8][4] = 128 regs (unified VGPR/AGPR file,
// 1 wave/SIMD so the 512-reg budget applies; R5 showed the compiler parks
// loop-invariant A-frags in AGPRs with no per-step copies). 16 MFMA/step =
// 8 independent 4-deep K-chains. v round-trips through wave-private LDS:
// lanes ci==mt write uint2 at element 16mt+4q (rows 16mt+4q+r), next step
// reads B-frags broadcast at 32kt+8q. Only lgkmcnt ordering -- NO barriers
// anywhere (removes the 4-wave __syncthreads + drain + skew ~350 cyc/step
// that dominated R0/R7's 1013 cyc step).
// y staged in 16 KB chunks via global_load_lds (16 issues/chunk, prefetch
// next chunk, vmcnt(16)) + in-place pre-exp pass. Renorm every 4 steps via
// deferred partials kept in a register (wave-local shfl reduce).
// bf16 pack = software RNE pkbf16 (proven; inline-asm cvt_pk NaN'd in R3).
// ---------------------------------------------------------------------------
__global__ __launch_bounds__(64, 1) void crf_chain_kernel(
    const float* __restrict__ y,
    const float* __restrict__ mask,
    const float* __restrict__ trans,
    float* __restrict__ vws,     // [B*2][128] end-state vectors (f32)
    float* __restrict__ cws)     // [B*2]      accumulated log-scales
{
    const int bd   = blockIdx.x;
    const int b    = bd >> 1;
    const int dir  = bd & 1;
    const int lane = threadIdx.x;    // 0..63 (one wave)
    const int q    = lane >> 4;
    const int ci   = lane & 15;

    __shared__ __align__(16) float eybuf[2][32 * K_];    // 2 x 16 KB y chunks
    __shared__ __align__(16) unsigned short vS[2][K_];   // v double buffer (bf16)

    const float* yb = y + (size_t)b * (T_ * K_);

    // ---- sequence length (mask is a contiguous 1.0 prefix) ----
    int L = 0;
    #pragma unroll
    for (int k = 0; k < 4; ++k) {
        unsigned long long bal = __ballot(mask[b * T_ + 64 * k + lane] != 0.0f);
        L += __popcll(bal);
    }
    const int H = L >> 1;
    const int nch = dir ? ((L - H + 31) >> 5) : ((H + 31) >> 5);

    auto stage = [&](int row0, int buf) {                // 16 global_load_lds
        const float* gp = yb + (size_t)row0 * K_;
        #pragma unroll
        for (int sg = 0; sg < 16; ++sg) {
            __builtin_amdgcn_global_load_lds(
                (gas1_t)(gp + sg * 256 + lane * 4),
                (las3_t)(&eybuf[buf][sg * 256]), 16, 0, 0);
        }
    };
    stage(dir ? (L - 32) : 0, 0);

    // ---- A-frags: FULL Texp. A[mt][kt]: lane(q,ci) = row 16mt+ci,
    //      k-elements 32kt+8q+j (R0-proven layout). backward: Texp^T.
    bf16x8 A[8][4];
    if (!dir) {
        #pragma unroll
        for (int mt = 0; mt < 8; ++mt) {
            const float* tp = trans + (16 * mt + ci) * K_;
            #pragma unroll
            for (int kt = 0; kt < 4; ++kt) {
                f32x4 p = *(const f32x4*)(tp + 32 * kt + 8 * q);
                f32x4 r = *(const f32x4*)(tp + 32 * kt + 8 * q + 4);
                uint4 u = make_uint4(pkbf16(__expf(p.x), __expf(p.y)),
                                     pkbf16(__expf(p.z), __expf(p.w)),
                                     pkbf16(__expf(r.x), __expf(r.y)),
                                     pkbf16(__expf(r.z), __expf(r.w)));
                A[mt][kt] = __builtin_bit_cast(bf16x8, u);
            }
        }
    } else {
        #pragma unroll
        for (int mt = 0; mt < 8; ++mt) {
            const int rowm = 16 * mt + ci;
            #pragma unroll
            for (int kt = 0; kt < 4; ++kt) {
                const float* cp = trans + (size_t)(32 * kt + 8 * q) * K_ + rowm;
                float e0 = __expf(cp[0 * K_]), e1 = __expf(cp[1 * K_]);
                float e2 = __expf(cp[2 * K_]), e3 = __expf(cp[3 * K_]);
                float e4 = __expf(cp[4 * K_]), e5 = __expf(cp[5 * K_]);
                float e6 = __expf(cp[6 * K_]), e7 = __expf(cp[7 * K_]);
                uint4 u = make_uint4(pkbf16(e0, e1), pkbf16(e2, e3),
                                     pkbf16(e4, e5), pkbf16(e6, e7));
                A[mt][kt] = __builtin_bit_cast(bf16x8, u);
            }
        }
    }

    // ---- state init: forward = one-hot SOS (elem 2 -> word 1 low half) ----
    if (!dir) ((unsigned int*)&vS[0][0])[lane] = (lane == 1) ? 0x3F80u : 0u;

    float c_acc = 0.0f;
    float Sred  = 1.0f;
    int cur = 0;
    int tstep = 0;

    auto step = [&](const float* eyp) {
        // B-frags: broadcast reads (16 ci-lanes same addr, conflict-free)
        const unsigned short* vp = vS[cur];
        bf16x8 Bf[4];
        #pragma unroll
        for (int kt = 0; kt < 4; ++kt)
            Bf[kt] = *(const bf16x8*)&vp[32 * kt + 8 * q];

        // ey for this lane's output rows 16mt+4q+r (pre-exp'd, broadcast)
        f32x4 ev[8];
        if (eyp) {
            #pragma unroll
            for (int mt = 0; mt < 8; ++mt)
                ev[mt] = *(const f32x4*)(eyp + 16 * mt + 4 * q);
        } else {
            #pragma unroll
            for (int mt = 0; mt < 8; ++mt)
                ev[mt] = (f32x4){1.f, 1.f, 1.f, 1.f};
        }

        // renorm: consume partial published at tstep-1 (register-carried)
        if (tstep && (tstep & 3) == 0) {
            const float rinv = __builtin_amdgcn_rcpf(Sred);
            c_acc += __logf(Sred);
            #pragma unroll
            for (int mt = 0; mt < 8; ++mt) ev[mt] *= rinv;
        }

        // 16 MFMA: 8 independent 4-deep K-chains
        f32x4 wv[8];
        #pragma unroll
        for (int mt = 0; mt < 8; ++mt) {
            f32x4 a = {0.f, 0.f, 0.f, 0.f};
            #pragma unroll
            for (int kt = 0; kt < 4; ++kt)
                a = __builtin_amdgcn_mfma_f32_16x16x32_bf16(A[mt][kt], Bf[kt], a, 0, 0, 0);
            wv[mt] = a * ev[mt];
        }

        if ((tstep & 3) == 3) {              // publish partial sum (2 shfl)
            float sp = 0.0f;
            #pragma unroll
            for (int mt = 0; mt < 8; ++mt)
                sp += (wv[mt].x + wv[mt].y) + (wv[mt].z + wv[mt].w);
            sp += __shfl_xor(sp, 16);
            sp += __shfl_xor(sp, 32);
            Sred = sp;
        }

        // pack + masked writes: lanes ci==mt write rows 16mt+4q+0..3
        unsigned short* wp = vS[cur ^ 1];
        #pragma unroll
        for (int mt = 0; mt < 8; ++mt) {
            uint2 d = make_uint2(pkbf16(wv[mt].x, wv[mt].y),
                                 pkbf16(wv[mt].z, wv[mt].w));
            if (ci == mt) *(uint2*)&wp[16 * mt + 4 * q] = d;
        }
        asm volatile("s_waitcnt lgkmcnt(0)" ::: "memory");
        __builtin_amdgcn_sched_barrier(0);   // rule 18: pin reads after wait
        cur ^= 1;
        ++tstep;
    };

    for (int c = 0; c < nch; ++c) {
        if (c + 1 < nch) {                   // prefetch next chunk (16 loads)
            stage(dir ? (L - 32 * (c + 2)) : (32 * (c + 1)), (c + 1) & 1);
            asm volatile("s_waitcnt vmcnt(16)" ::: "memory");  // chunk c done
        } else {
            asm volatile("s_waitcnt vmcnt(0)" ::: "memory");
        }
        __builtin_amdgcn_sched_barrier(0);
        float* bp = eybuf[c & 1];
        #pragma unroll
        for (int i = 0; i < 16; ++i) {       // pre-exp pass (4096 floats/wave)
            f32x4 v4 = *(const f32x4*)(bp + (i * 64 + lane) * 4);
            v4.x = __expf(v4.x); v4.y = __expf(v4.y);
            v4.z = __expf(v4.z); v4.w = __expf(v4.w);
            *(f32x4*)(bp + (i * 64 + lane) * 4) = v4;
        }
        asm volatile("s_waitcnt lgkmcnt(0)" ::: "memory");
        __builtin_amdgcn_sched_barrier(0);

        if (!dir) {                          // rows t = 32c + li, ascending
            const int ns = (H - 32 * c) < 32 ? (H - 32 * c) : 32;
            for (int li = 0; li < ns; ++li) step(bp + li * K_);
        } else {
            if (c == 0) {                    // init z = ey_{L-1} (row 31)
                float a0 = bp[31 * K_ + 2 * lane];
                float a1 = bp[31 * K_ + 2 * lane + 1];
                ((unsigned int*)&vS[0][0])[lane] = pkbf16(a0, a1);
                asm volatile("s_waitcnt lgkmcnt(0)" ::: "memory");
                __builtin_amdgcn_sched_barrier(0);
            }
            const int base = L - 32 * (c + 1);
            const int ls = (c == 0) ? 30 : 31;           // li=31 of c=0 was init
            int le = H - base; if (le < 0) le = 0;       // stop at t = H
            for (int li = ls; li >= le; --li) step(bp + li * K_);
        }
    }
    if (dir) step(nullptr);                  // final unscaled Texp^T application

    // ---- store end state (bf16 widened to f32) + log-scale ----
    {
        unsigned int uv = ((const unsigned int*)&vS[cur][0])[lane];
        vws[(size_t)bd * K_ + 2 * lane]     = __builtin_bit_cast(float, uv << 16);
        vws[(size_t)bd * K_ + 2 * lane + 1] = __builtin_bit_cast(float, uv & 0xFFFF0000u);
    }
    if (lane == 0) cws[bd] = c_acc;
}

// ---------------------------------------------------------------------------
// Combine: out[b] = c_f + c_b + log( v_H . w )
// ---------------------------------------------------------------------------
__global__ __launch_bounds__(128) void crf_comb_kernel(
    const float* __restrict__ vws,
    const float* __restrict__ cws,
    float* __restrict__ out)
{
    const int b   = blockIdx.x;
    const int tid = threadIdx.x;             // 0..127
    __shared__ float red2[2];

    float p = vws[(size_t)(2 * b) * K_ + tid] * vws[(size_t)(2 * b + 1) * K_ + tid];
    p += __shfl_xor(p, 1);  p += __shfl_xor(p, 2);
    p += __shfl_xor(p, 4);  p += __shfl_xor(p, 8);
    p += __shfl_xor(p, 16); p += __shfl_xor(p, 32);
    if ((tid & 63) == 0) red2[tid >> 6] = p;
    __syncthreads();
    if (tid == 0) out[b] = cws[2 * b] + cws[2 * b + 1] + __logf(red2[0] + red2[1]);
}

extern "C" void kernel_launch(void* const* d_in, const int* in_sizes, int n_in,
                              void* d_out, int out_size, void* d_ws, size_t ws_size,
                              hipStream_t stream) {
    const float* y     = (const float*)d_in[0];   // (B, T, K) fp32
    const float* mask  = (const float*)d_in[1];   // (B, T)    fp32 0/1
    const float* trans = (const float*)d_in[2];   // (K, K)    fp32
    float* out = (float*)d_out;                   // (B,)      fp32

    float* vws = (float*)d_ws;                              // 64 KB
    float* cws = (float*)((char*)d_ws + (size_t)B_ * 2 * K_ * sizeof(float));

    crf_chain_kernel<<<B_ * 2, 64, 0, stream>>>(y, mask, trans, vws, cws);
    crf_comb_kernel<<<B_, 128, 0, stream>>>(vws, cws, out);
}

// Round 9
// 114.266 us; speedup vs baseline: 1.6655x; 1.6655x over previous
//
#include <hip/hip_runtime.h>
#include <math.h>

#define B_ 64
#define T_ 256
#define K_ 128

typedef const __attribute__((address_space(1))) void* gas1_t;
typedef __attribute__((address_space(3))) void* las3_t;
typedef float f32x4 __attribute__((ext_vector_type(4)));
typedef short bf16x8 __attribute__((ext_vector_type(8)));

static __device__ __forceinline__ unsigned int bf16rne(float x) {
    unsigned int u = __builtin_bit_cast(unsigned int, x);
    return (u + 0x7FFFu + ((u >> 16) & 1u)) >> 16;
}
static __device__ __forceinline__ unsigned int pkbf16(float a, float b) {
    return bf16rne(a) | (bf16rne(b) << 16);
}

// Producer side of every LDS exchange: own ds_writes committed, then barrier.
// (NOT __syncthreads: that drains vmcnt(0) too, killing the chunk prefetch
// at every step barrier -- T4: never drain vmcnt in the main loop.)
#define LGKM_BARRIER()                                        \
    do {                                                      \
        asm volatile("s_waitcnt lgkmcnt(0)" ::: "memory");    \
        __builtin_amdgcn_s_barrier();                         \
        __builtin_amdgcn_sched_barrier(0);                    \
    } while (0)

// ---------------------------------------------------------------------------
// Bidirectional matvec chains (R7 structure, 4 waves/block, proven 54 us),
// with precise-waitcnt raw barriers and split-K MFMA chains.
//   forward  (dir=0): v_H = prod_{t=H..1} D_t Texp  e_SOS          (H steps)
//   backward (dir=1): z = ey_{L-1}; z <- ey_t (.) Texp^T z, t=L-2..H;
//                     w = Texp^T z                                  (L-H steps)
//   out = c_f + c_b + log(v_H . w)   (combine kernel)
// Wave w owns rows [32w,32w+32): 2 mt x 4 kt = 8 MFMA/step (2 chains, each
// split 2+2 and summed -> dep depth 2). v exchanged via double-buffered LDS;
// y staged in 16KB chunks via global_load_lds with counted vmcnt(4) prefetch
// that now STAYS IN FLIGHT across all 32 step barriers.
// ---------------------------------------------------------------------------
__global__ __launch_bounds__(256) void crf_chain_kernel(
    const float* __restrict__ y,
    const float* __restrict__ mask,
    const float* __restrict__ trans,
    float* __restrict__ vws,     // [B*2][128] end-state vectors (f32)
    float* __restrict__ cws)     // [B*2]      accumulated log-scales
{
    const int bd   = blockIdx.x;
    const int b    = bd >> 1;
    const int dir  = bd & 1;
    const int tid  = threadIdx.x;
    const int w    = tid >> 6;
    const int lane = tid & 63;
    const int q    = lane >> 4;
    const int ci   = lane & 15;

    __shared__ __align__(16) float eybuf[2][32 * K_];    // 2 x 16 KB y chunks
    __shared__ __align__(16) unsigned short vS[2][K_];   // v double buffer (bf16)
    __shared__ __align__(16) float wsumS[4];             // deferred renorm partials
    __shared__ int lenS[4];

    const float* yb = y + (size_t)b * (T_ * K_);

    // ---- sequence length first (backward staging needs L) ----
    {
        float mval = mask[b * T_ + tid];
        unsigned long long bal = __ballot(mval != 0.0f);
        if (lane == 0) lenS[w] = __popcll(bal);
    }
    __syncthreads();                         // once, outside the hot loop
    const int L = lenS[0] + lenS[1] + lenS[2] + lenS[3];   // in [128, 256]
    const int H = L >> 1;
    const int nch = dir ? ((L - H + 31) >> 5) : ((H + 31) >> 5);

    auto stage = [&](int row0, int buf) {                // 4 global_load_lds/wave
        const float* gp = yb + (size_t)row0 * K_;
        #pragma unroll
        for (int s4 = 0; s4 < 4; ++s4) {
            const int seg = 4 * w + s4;                  // 16 segments x 1 KB
            __builtin_amdgcn_global_load_lds(
                (gas1_t)(gp + seg * 256 + lane * 4),
                (las3_t)(&eybuf[buf][seg * 256]), 16, 0, 0);
        }
    };
    stage(dir ? (L - 32) : 0, 0);

    // ---- A-frags: A[m=ci][k=8q+j] for rows 32w+16mt+ci (R0-proven layout) ----
    // forward: A = Texp (row-major reads); backward: A = Texp^T (strided, once)
    bf16x8 A[2][4];
    if (!dir) {
        #pragma unroll
        for (int mt = 0; mt < 2; ++mt) {
            const float* tp = trans + (32 * w + 16 * mt + ci) * K_;
            #pragma unroll
            for (int kt = 0; kt < 4; ++kt) {
                f32x4 p = *(const f32x4*)(tp + 32 * kt + 8 * q);
                f32x4 r = *(const f32x4*)(tp + 32 * kt + 8 * q + 4);
                uint4 u = make_uint4(pkbf16(__expf(p.x), __expf(p.y)),
                                     pkbf16(__expf(p.z), __expf(p.w)),
                                     pkbf16(__expf(r.x), __expf(r.y)),
                                     pkbf16(__expf(r.z), __expf(r.w)));
                A[mt][kt] = __builtin_bit_cast(bf16x8, u);
            }
        }
    } else {
        #pragma unroll
        for (int mt = 0; mt < 2; ++mt) {
            const int rowm = 32 * w + 16 * mt + ci;
            #pragma unroll
            for (int kt = 0; kt < 4; ++kt) {
                const float* cp = trans + (size_t)(32 * kt + 8 * q) * K_ + rowm;
                float e0 = __expf(cp[0 * K_]), e1 = __expf(cp[1 * K_]);
                float e2 = __expf(cp[2 * K_]), e3 = __expf(cp[3 * K_]);
                float e4 = __expf(cp[4 * K_]), e5 = __expf(cp[5 * K_]);
                float e6 = __expf(cp[6 * K_]), e7 = __expf(cp[7 * K_]);
                uint4 u = make_uint4(pkbf16(e0, e1), pkbf16(e2, e3),
                                     pkbf16(e4, e5), pkbf16(e6, e7));
                A[mt][kt] = __builtin_bit_cast(bf16x8, u);
            }
        }
    }

    // ---- state init: forward = one-hot SOS. ALL waves write the full vector
    //      redundantly (identical values) so each wave's own lgkm drain at the
    //      next barrier guarantees visibility without a full __syncthreads.
    if (!dir) ((unsigned int*)&vS[0][0])[lane] = (lane == 1) ? 0x3F80u : 0u;

    float c_acc = 0.0f;
    int cur = 0;
    int tstep = 0;

    auto step = [&](const float* eyp) {
        const unsigned short* vp = vS[cur];
        bf16x8 Bf[4];
        #pragma unroll
        for (int kt = 0; kt < 4; ++kt)
            Bf[kt] = *(const bf16x8*)&vp[32 * kt + 8 * q];

        f32x4 ey0, ey1;
        if (eyp) {
            ey0 = *(const f32x4*)(eyp + 32 * w + 4 * q);
            ey1 = *(const f32x4*)(eyp + 32 * w + 4 * q + 16);
        } else {
            ey0 = (f32x4){1.f, 1.f, 1.f, 1.f};
            ey1 = ey0;
        }

        // split-K: two 2-deep chains per output tile, summed (dep depth 4->2)
        f32x4 a0 = {0.f, 0.f, 0.f, 0.f}, a0b = {0.f, 0.f, 0.f, 0.f};
        f32x4 a1 = {0.f, 0.f, 0.f, 0.f}, a1b = {0.f, 0.f, 0.f, 0.f};
        a0  = __builtin_amdgcn_mfma_f32_16x16x32_bf16(A[0][0], Bf[0], a0,  0, 0, 0);
        a1  = __builtin_amdgcn_mfma_f32_16x16x32_bf16(A[1][0], Bf[0], a1,  0, 0, 0);
        a0b = __builtin_amdgcn_mfma_f32_16x16x32_bf16(A[0][2], Bf[2], a0b, 0, 0, 0);
        a1b = __builtin_amdgcn_mfma_f32_16x16x32_bf16(A[1][2], Bf[2], a1b, 0, 0, 0);
        a0  = __builtin_amdgcn_mfma_f32_16x16x32_bf16(A[0][1], Bf[1], a0,  0, 0, 0);
        a1  = __builtin_amdgcn_mfma_f32_16x16x32_bf16(A[1][1], Bf[1], a1,  0, 0, 0);
        a0b = __builtin_amdgcn_mfma_f32_16x16x32_bf16(A[0][3], Bf[3], a0b, 0, 0, 0);
        a1b = __builtin_amdgcn_mfma_f32_16x16x32_bf16(A[1][3], Bf[3], a1b, 0, 0, 0);
        f32x4 w0 = (a0 + a0b) * ey0;
        f32x4 w1 = (a1 + a1b) * ey1;

        if (tstep && (tstep & 3) == 0) {     // consume partials from tstep-1
            f32x4 ws = *(const f32x4*)wsumS;
            float S = (ws.x + ws.y) + (ws.z + ws.w);
            float rinv = __builtin_amdgcn_rcpf(S);
            c_acc += __logf(S);
            w0 *= rinv; w1 *= rinv;
        }
        if ((tstep & 3) == 3) {              // publish partial sums
            f32x4 sv = w0 + w1;
            float sp = (sv.x + sv.y) + (sv.z + sv.w);
            sp += __shfl_xor(sp, 16);
            sp += __shfl_xor(sp, 32);
            if (lane == 0) wsumS[w] = sp;
        }
        if (ci == 0) {                       // 8 x 8B writes per wave
            uint2 d0 = make_uint2(pkbf16(w0.x, w0.y), pkbf16(w0.z, w0.w));
            uint2 d1 = make_uint2(pkbf16(w1.x, w1.y), pkbf16(w1.z, w1.w));
            *(uint2*)&vS[cur ^ 1][32 * w + 4 * q]      = d0;
            *(uint2*)&vS[cur ^ 1][32 * w + 16 + 4 * q] = d1;
        }
        LGKM_BARRIER();                      // writes visible; vmcnt untouched
        cur ^= 1;
        ++tstep;
    };

    for (int c = 0; c < nch; ++c) {
        if (c + 1 < nch) {                   // prefetch next chunk
            stage(dir ? (L - 32 * (c + 2)) : (32 * (c + 1)), (c + 1) & 1);
            asm volatile("s_waitcnt vmcnt(4)" ::: "memory");   // chunk c's 4 done
        } else {
            asm volatile("s_waitcnt vmcnt(0)" ::: "memory");
        }
        LGKM_BARRIER();                      // all waves' DMA (+init) visible
        float* bp = eybuf[c & 1];
        #pragma unroll
        for (int i = 0; i < 4; ++i) {        // pre-exp pass (4096 floats/256 thr)
            f32x4 v4 = *(const f32x4*)(bp + i * 1024 + tid * 4);
            v4.x = __expf(v4.x); v4.y = __expf(v4.y);
            v4.z = __expf(v4.z); v4.w = __expf(v4.w);
            *(f32x4*)(bp + i * 1024 + tid * 4) = v4;
        }
        LGKM_BARRIER();                      // exp'd chunk visible to all waves

        if (!dir) {                          // rows t = 32c + li, ascending
            const int ns = (H - 32 * c) < 32 ? (H - 32 * c) : 32;
            for (int li = 0; li < ns; ++li) step(bp + li * K_);
        } else {
            if (c == 0) {                    // init z = ey_{L-1} (row 31):
                float a0 = bp[31 * K_ + 2 * lane];     // all waves write the
                float a1 = bp[31 * K_ + 2 * lane + 1]; // same 64 words redundantly
                ((unsigned int*)&vS[0][0])[lane] = pkbf16(a0, a1);
                asm volatile("s_waitcnt lgkmcnt(0)" ::: "memory");
                __builtin_amdgcn_sched_barrier(0);
            }
            const int base = L - 32 * (c + 1);
            const int ls = (c == 0) ? 30 : 31;          // li=31 of c=0 was init
            int le = H - base; if (le < 0) le = 0;      // stop at t = H
            for (int li = ls; li >= le; --li) step(bp + li * K_);
        }
    }
    if (dir) step(nullptr);                  // final unscaled Texp^T application

    // ---- store end state (bf16 widened to f32) + log-scale ----
    if (tid < K_) {
        unsigned int hv = vS[cur][tid];
        vws[(size_t)bd * K_ + tid] = __builtin_bit_cast(float, hv << 16);
    }
    if (tid == 0) cws[bd] = c_acc;
}

// ---------------------------------------------------------------------------
// Combine: out[b] = c_f + c_b + log( v_H . w )
// ---------------------------------------------------------------------------
__global__ __launch_bounds__(128) void crf_comb_kernel(
    const float* __restrict__ vws,
    const float* __restrict__ cws,
    float* __restrict__ out)
{
    const int b   = blockIdx.x;
    const int tid = threadIdx.x;             // 0..127
    __shared__ float red2[2];

    float p = vws[(size_t)(2 * b) * K_ + tid] * vws[(size_t)(2 * b + 1) * K_ + tid];
    p += __shfl_xor(p, 1);  p += __shfl_xor(p, 2);
    p += __shfl_xor(p, 4);  p += __shfl_xor(p, 8);
    p += __shfl_xor(p, 16); p += __shfl_xor(p, 32);
    if ((tid & 63) == 0) red2[tid >> 6] = p;
    __syncthreads();
    if (tid == 0) out[b] = cws[2 * b] + cws[2 * b + 1] + __logf(red2[0] + red2[1]);
}

extern "C" void kernel_launch(void* const* d_in, const int* in_sizes, int n_in,
                              void* d_out, int out_size, void* d_ws, size_t ws_size,
                              hipStream_t stream) {
    const float* y     = (const float*)d_in[0];   // (B, T, K) fp32
    const float* mask  = (const float*)d_in[1];   // (B, T)    fp32 0/1
    const float* trans = (const float*)d_in[2];   // (K, K)    fp32
    float* out = (float*)d_out;                   // (B,)      fp32

    float* vws = (float*)d_ws;                              // 64 KB
    float* cws = (float*)((char*)d_ws + (size_t)B_ * 2 * K_ * sizeof(float));

    crf_chain_kernel<<<B_ * 2, 256, 0, stream>>>(y, mask, trans, vws, cws);
    crf_comb_kernel<<<B_, 128, 0, stream>>>(vws, cws, out);
}